// Round 2
// baseline (818.737 us; speedup 1.0000x reference)
//
#include <hip/hip_runtime.h>
#include <hip/hip_cooperative_groups.h>

namespace cg = cooperative_groups;

#define NBATCH 128
#define NITER 10
#define BLKT 1024  // threads per block (8 node slots x 128 batch lanes)

// ---------------- setup kernels ----------------

__global__ void zero_kernel(uint32_t* __restrict__ p, int n) {
  int i = blockIdx.x * blockDim.x + threadIdx.x;
  if (i < n) p[i] = 0u;
}

__global__ void hist_kernel(const int* __restrict__ src, const int* __restrict__ tgt,
                            int* __restrict__ cntS, int* __restrict__ cntT, int E) {
  int e = blockIdx.x * blockDim.x + threadIdx.x;
  if (e < E) {
    atomicAdd(&cntS[src[e]], 1);
    atomicAdd(&cntT[tgt[e]], 1);
  }
}

// exclusive prefix sum of PADDED counts (pad each node's degree to multiple of 4)
// blockIdx.x 0 -> S, 1 -> T ; 256 threads x 8 = 2048 >= N+1
__global__ void scan_pad_kernel(const int* __restrict__ cntS, const int* __restrict__ cntT,
                                int* __restrict__ offS, int* __restrict__ offT,
                                int* __restrict__ curS, int* __restrict__ curT, int N) {
  const int* cnt = (blockIdx.x == 0) ? cntS : cntT;
  int* off = (blockIdx.x == 0) ? offS : offT;
  int* cur = (blockIdx.x == 0) ? curS : curT;
  __shared__ int tsum[256];
  int tid = threadIdx.x;
  int base = tid * 8;
  int v[8];
  int s = 0;
#pragma unroll
  for (int i = 0; i < 8; ++i) {
    int idx = base + i;
    int c = (idx < N) ? ((cnt[idx] + 3) & ~3) : 0;  // padded degree
    v[i] = s;
    s += c;
  }
  tsum[tid] = s;
  __syncthreads();
  for (int d = 1; d < 256; d <<= 1) {
    int t = (tid >= d) ? tsum[tid - d] : 0;
    __syncthreads();
    tsum[tid] += t;
    __syncthreads();
  }
  int tbase = tsum[tid] - s;
#pragma unroll
  for (int i = 0; i < 8; ++i) {
    int idx = base + i;
    if (idx < N) {
      int o = tbase + v[i];
      off[idx] = o;
      cur[idx] = o;
    } else if (idx == N) {
      off[idx] = tbase + v[i];
    }
  }
}

// pack: low 16 = neighbor index, high 16 = bf16(w) bits (so w = uint_as_float(v & 0xFFFF0000))
__device__ __forceinline__ uint32_t bf16_hi_bits(float f) {
  uint32_t b = __float_as_uint(f);
  b += 0x7FFFu + ((b >> 16) & 1u);  // round-to-nearest-even to bf16
  return b & 0xFFFF0000u;
}

__global__ void scatter_kernel(const int* __restrict__ src, const int* __restrict__ tgt,
                               const float* __restrict__ w,
                               int* __restrict__ curS, int* __restrict__ curT,
                               uint32_t* __restrict__ edgeS, uint32_t* __restrict__ edgeT, int E) {
  int e = blockIdx.x * blockDim.x + threadIdx.x;
  if (e < E) {
    int s = src[e], t = tgt[e];
    uint32_t wb = bf16_hi_bits(w[e]);
    int p = atomicAdd(&curS[s], 1);
    edgeS[p] = (uint32_t)t | wb;  // mu pass: grouped by src, gathers fx[tgt]
    int q = atomicAdd(&curT[t], 1);
    edgeT[q] = (uint32_t)s | wb;  // agg pass: grouped by tgt, gathers err[src]
  }
}

// ---------------- cooperative main kernel ----------------

__device__ __forceinline__ float bf2f(unsigned short u) {
  return __uint_as_float(((uint32_t)u) << 16);
}

__device__ __forceinline__ unsigned short f2bf(float f) {
  uint32_t b = __float_as_uint(f);
  b += 0x7FFFu + ((b >> 16) & 1u);
  return (unsigned short)(b >> 16);
}

// CSR segment [p0,p1) is padded to a multiple of 4 (pad entries are idx=0,w=+0.0)
__device__ __forceinline__ float gather4(const uint32_t* __restrict__ ed, int p0, int p1,
                                         const unsigned short* __restrict__ buf, int b) {
  float a0 = 0.f, a1 = 0.f, a2 = 0.f, a3 = 0.f;
  for (int p = p0; p < p1; p += 4) {
    uint32_t e0 = ed[p + 0], e1 = ed[p + 1], e2 = ed[p + 2], e3 = ed[p + 3];
    a0 = fmaf(__uint_as_float(e0 & 0xFFFF0000u), bf2f(buf[(e0 & 0xFFFFu) * NBATCH + b]), a0);
    a1 = fmaf(__uint_as_float(e1 & 0xFFFF0000u), bf2f(buf[(e1 & 0xFFFFu) * NBATCH + b]), a1);
    a2 = fmaf(__uint_as_float(e2 & 0xFFFF0000u), bf2f(buf[(e2 & 0xFFFFu) * NBATCH + b]), a2);
    a3 = fmaf(__uint_as_float(e3 & 0xFFFF0000u), bf2f(buf[(e3 & 0xFFFFu) * NBATCH + b]), a3);
  }
  return (a0 + a1) + (a2 + a3);
}

__global__ __launch_bounds__(BLKT, 4) void pc_loop_kernel(
    const float* __restrict__ x, float* __restrict__ out,
    const int* __restrict__ offS, const uint32_t* __restrict__ edgeS,
    const int* __restrict__ offT, const uint32_t* __restrict__ edgeT,
    unsigned short* __restrict__ fxb, unsigned short* __restrict__ errb,
    const float* __restrict__ mask, int N) {
  cg::grid_group grid = cg::this_grid();
  const int tid = threadIdx.x;
  const int slot = tid >> 7;
  const int b = tid & (NBATCH - 1);
  const int n = blockIdx.x * (BLKT / NBATCH) + slot;
  const bool act = (n < N);

  float m = 0.f, xc = 0.f, fx = 0.f;
  int s0 = 0, s1 = 0, t0 = 0, t1 = 0, i = 0;
  if (act) {
    i = n * NBATCH + b;
    m = mask[n];
    s0 = offS[n]; s1 = offS[n + 1];
    t0 = offT[n]; t1 = offT[n + 1];
    xc = x[b * N + n];          // transpose-in: x stays register-resident
    fx = tanhf(xc);
    fxb[i] = f2bf(fx);          // publish fx row (bf16)
  }
  grid.sync();

  for (int it = 0; it < NITER; ++it) {
    float err = 0.f;
    if (act) {
      float mu = gather4(edgeS, s0, s1, fxb, b);
      err = (xc - mu) * m;
      errb[i] = f2bf(err);      // publish err row (bf16)
    }
    grid.sync();
    if (act) {
      float agg = gather4(edgeT, t0, t1, errb, b);
      float dx = err - (1.f - fx * fx) * agg;  // err kept fp32 locally
      xc = xc - 0.5f * dx * m;
      fx = tanhf(xc);
      if (it < NITER - 1) fxb[i] = f2bf(fx);
    }
    if (it < NITER - 1) grid.sync();
  }

  if (act) out[b * N + n] = xc;  // transpose-out from registers
}

// ---------------- host ----------------

extern "C" void kernel_launch(void* const* d_in, const int* in_sizes, int n_in,
                              void* d_out, int out_size, void* d_ws, size_t ws_size,
                              hipStream_t stream) {
  const float* x = (const float*)d_in[0];
  const int* ei = (const int*)d_in[1];
  const float* w = (const float*)d_in[2];
  const float* mask = (const float*)d_in[3];
  const int E = in_sizes[2];      // 131072
  int N = in_sizes[3];            // 2000
  const int* src = ei;
  const int* tgt = ei + E;
  float* out = (float*)d_out;

  const int Epad = E + 4 * N;     // room for per-node pad-to-4

  size_t off = 0;
  auto alloc = [&](size_t bytes) -> void* {
    off = (off + 255) & ~(size_t)255;
    void* p = (char*)d_ws + off;
    off += bytes;
    return p;
  };
  // keep cntS,cntT,edgeS,edgeT contiguous (sizes are 256B multiples) so one zero pass covers all
  int* cntS = (int*)alloc(2048 * 4);
  int* cntT = (int*)alloc(2048 * 4);
  uint32_t* edgeS = (uint32_t*)alloc((size_t)Epad * 4);
  uint32_t* edgeT = (uint32_t*)alloc((size_t)Epad * 4);
  int* offS = (int*)alloc(2048 * 4);
  int* offT = (int*)alloc(2048 * 4);
  int* curS = (int*)alloc(2048 * 4);
  int* curT = (int*)alloc(2048 * 4);
  unsigned short* fxb = (unsigned short*)alloc((size_t)N * NBATCH * 2);
  unsigned short* errb = (unsigned short*)alloc((size_t)N * NBATCH * 2);

  const int nzero = (int)(((char*)offS - (char*)cntS) / 4);  // cnts + both edge arrays
  zero_kernel<<<(nzero + 255) / 256, 256, 0, stream>>>((uint32_t*)cntS, nzero);
  hist_kernel<<<(E + 255) / 256, 256, 0, stream>>>(src, tgt, cntS, cntT, E);
  scan_pad_kernel<<<2, 256, 0, stream>>>(cntS, cntT, offS, offT, curS, curT, N);
  scatter_kernel<<<(E + 255) / 256, 256, 0, stream>>>(src, tgt, w, curS, curT, edgeS, edgeT, E);

  const int blocks = (N * NBATCH + BLKT - 1) / BLKT;  // 250
  void* args[] = {(void*)&x,    (void*)&out,  (void*)&offS, (void*)&edgeS, (void*)&offT,
                  (void*)&edgeT, (void*)&fxb, (void*)&errb, (void*)&mask,  (void*)&N};
  hipLaunchCooperativeKernel((const void*)pc_loop_kernel, dim3(blocks), dim3(BLKT), args, 0,
                             stream);
}

// Round 3
// 226.046 us; speedup vs baseline: 3.6220x; 3.6220x over previous
//
#include <hip/hip_runtime.h>

#define NBATCH 128
#define NITER 10
#define PAD 8  // CSR segment padding / accumulator depth

// ---------------- helpers ----------------

__device__ __forceinline__ float bf2f_lo(uint32_t v) { return __uint_as_float(v << 16); }
__device__ __forceinline__ float bf2f_hi(uint32_t v) { return __uint_as_float(v & 0xFFFF0000u); }

__device__ __forceinline__ uint32_t f2bf_bits(float f) {  // round-to-nearest-even, top 16 bits
  uint32_t b = __float_as_uint(f);
  b += 0x7FFFu + ((b >> 16) & 1u);
  return b >> 16;
}
__device__ __forceinline__ uint32_t pack_bf16x2(float lo, float hi) {
  return f2bf_bits(lo) | (f2bf_bits(hi) << 16);
}

// ---------------- setup kernels ----------------

__global__ void zero_kernel(uint32_t* __restrict__ p, int n) {
  int i = blockIdx.x * blockDim.x + threadIdx.x;
  if (i < n) p[i] = 0u;
}

__global__ void hist_kernel(const int* __restrict__ src, const int* __restrict__ tgt,
                            int* __restrict__ cntS, int* __restrict__ cntT, int E) {
  int e = blockIdx.x * blockDim.x + threadIdx.x;
  if (e < E) {
    atomicAdd(&cntS[src[e]], 1);
    atomicAdd(&cntT[tgt[e]], 1);
  }
}

// exclusive prefix sum of counts padded to multiple of PAD.
// blockIdx.x 0 -> S, 1 -> T ; 256 threads x 8 = 2048 >= N+1
__global__ void scan_pad_kernel(const int* __restrict__ cntS, const int* __restrict__ cntT,
                                int* __restrict__ offS, int* __restrict__ offT,
                                int* __restrict__ curS, int* __restrict__ curT, int N) {
  const int* cnt = (blockIdx.x == 0) ? cntS : cntT;
  int* off = (blockIdx.x == 0) ? offS : offT;
  int* cur = (blockIdx.x == 0) ? curS : curT;
  __shared__ int tsum[256];
  int tid = threadIdx.x;
  int base = tid * 8;
  int v[8];
  int s = 0;
#pragma unroll
  for (int i = 0; i < 8; ++i) {
    int idx = base + i;
    int c = (idx < N) ? ((cnt[idx] + (PAD - 1)) & ~(PAD - 1)) : 0;
    v[i] = s;
    s += c;
  }
  tsum[tid] = s;
  __syncthreads();
  for (int d = 1; d < 256; d <<= 1) {
    int t = (tid >= d) ? tsum[tid - d] : 0;
    __syncthreads();
    tsum[tid] += t;
    __syncthreads();
  }
  int tbase = tsum[tid] - s;
#pragma unroll
  for (int i = 0; i < 8; ++i) {
    int idx = base + i;
    if (idx < N) {
      int o = tbase + v[i];
      off[idx] = o;
      cur[idx] = o;
    } else if (idx == N) {
      off[idx] = tbase + v[i];
    }
  }
}

// pack edge: low 16 = neighbor index, high 16 = bf16(w) bits
__global__ void scatter_kernel(const int* __restrict__ src, const int* __restrict__ tgt,
                               const float* __restrict__ w,
                               int* __restrict__ curS, int* __restrict__ curT,
                               uint32_t* __restrict__ edgeS, uint32_t* __restrict__ edgeT, int E) {
  int e = blockIdx.x * blockDim.x + threadIdx.x;
  if (e < E) {
    int s = src[e], t = tgt[e];
    uint32_t wb = __float_as_uint(w[e]);
    wb = (wb + 0x7FFFu + ((wb >> 16) & 1u)) & 0xFFFF0000u;  // bf16 bits in high half
    int p = atomicAdd(&curS[s], 1);
    edgeS[p] = (uint32_t)t | wb;  // mu pass: grouped by src, gathers fx[tgt]
    int q = atomicAdd(&curT[t], 1);
    edgeT[q] = (uint32_t)s | wb;  // agg pass: grouped by tgt, gathers err[src]
  }
}

// x[b*N+n] -> xt2[n*64+l] = (x[2l, n], x[2l+1, n]); fx32 = packed bf16(tanh(x))
__global__ void tin_kernel(const float* __restrict__ x, float2* __restrict__ xt2,
                           uint32_t* __restrict__ fx32, int N) {
  int gid = blockIdx.x * blockDim.x + threadIdx.x;  // over N*64
  if (gid >= N * 64) return;
  int n = gid >> 6, l = gid & 63;
  float v0 = x[(2 * l) * N + n];
  float v1 = x[(2 * l + 1) * N + n];
  xt2[gid] = make_float2(v0, v1);
  fx32[gid] = pack_bf16x2(tanhf(v0), tanhf(v1));
}

__global__ void tout_kernel(const float2* __restrict__ xt2, float* __restrict__ out, int N) {
  int gid = blockIdx.x * blockDim.x + threadIdx.x;  // = b*N + n (coalesced write)
  if (gid >= N * NBATCH) return;
  int b = gid / N;
  int n = gid - b * N;
  float2 v = xt2[n * 64 + (b >> 1)];
  out[gid] = (b & 1) ? v.y : v.x;
}

// ---------------- main loop kernels ----------------
// One wave (64 lanes) per node; lane l handles batch elements 2l, 2l+1.
// CSR segments are padded to PAD (pad entries idx=0, w=+0.0) and 32B-aligned.

__device__ __forceinline__ void gather_pad8(const uint32_t* __restrict__ ed, int p0, int p1,
                                            const uint32_t* __restrict__ buf, int lane,
                                            float& out0, float& out1) {
  float a0[PAD], a1[PAD];
#pragma unroll
  for (int j = 0; j < PAD; ++j) { a0[j] = 0.f; a1[j] = 0.f; }
  for (int p = p0; p < p1; p += PAD) {
    const uint4* ed4 = (const uint4*)(ed + p);
    uint4 ea = ed4[0];
    uint4 eb = ed4[1];
    uint32_t e[PAD] = {ea.x, ea.y, ea.z, ea.w, eb.x, eb.y, eb.z, eb.w};
#pragma unroll
    for (int j = 0; j < PAD; ++j) {
      uint32_t v = buf[((e[j] & 0xFFFFu) << 6) + lane];
      float wj = __uint_as_float(e[j] & 0xFFFF0000u);
      a0[j] = fmaf(wj, bf2f_lo(v), a0[j]);
      a1[j] = fmaf(wj, bf2f_hi(v), a1[j]);
    }
  }
  out0 = ((a0[0] + a0[1]) + (a0[2] + a0[3])) + ((a0[4] + a0[5]) + (a0[6] + a0[7]));
  out1 = ((a1[0] + a1[1]) + (a1[2] + a1[3])) + ((a1[4] + a1[5]) + (a1[6] + a1[7]));
}

// phase1: mu[n] = sum_{e: src==n} w*fx[tgt]; err[n] = (x[n]-mu)*mask[n]
__global__ __launch_bounds__(256) void phase1_kernel(
    const float2* __restrict__ xt2, const uint32_t* __restrict__ fx32,
    float2* __restrict__ errf2, uint32_t* __restrict__ err32,
    const int* __restrict__ offS, const uint32_t* __restrict__ edS,
    const float* __restrict__ mask, int N) {
  const int lane = threadIdx.x & 63;
  const int n = blockIdx.x * 4 + (threadIdx.x >> 6);
  if (n >= N) return;
  float mu0, mu1;
  gather_pad8(edS, offS[n], offS[n + 1], fx32, lane, mu0, mu1);
  const int i = (n << 6) + lane;
  const float2 xc = xt2[i];
  const float m = mask[n];
  const float e0 = (xc.x - mu0) * m;
  const float e1 = (xc.y - mu1) * m;
  errf2[i] = make_float2(e0, e1);
  err32[i] = pack_bf16x2(e0, e1);
}

// phase2: agg[n] = sum_{e: tgt==n} w*err[src]; dx = err - (1-tanh(x)^2)*agg;
//         x -= 0.5*dx*mask; fx = tanh(x)
__global__ __launch_bounds__(256) void phase2_kernel(
    float2* __restrict__ xt2, uint32_t* __restrict__ fx32,
    const float2* __restrict__ errf2, const uint32_t* __restrict__ err32,
    const int* __restrict__ offT, const uint32_t* __restrict__ edT,
    const float* __restrict__ mask, int N) {
  const int lane = threadIdx.x & 63;
  const int n = blockIdx.x * 4 + (threadIdx.x >> 6);
  if (n >= N) return;
  float ag0, ag1;
  gather_pad8(edT, offT[n], offT[n + 1], err32, lane, ag0, ag1);
  const int i = (n << 6) + lane;
  const float2 xc = xt2[i];
  const float2 er = errf2[i];
  const float m = mask[n];
  const float fx0 = tanhf(xc.x);
  const float fx1 = tanhf(xc.y);
  const float dx0 = er.x - (1.f - fx0 * fx0) * ag0;
  const float dx1 = er.y - (1.f - fx1 * fx1) * ag1;
  const float xn0 = xc.x - 0.5f * dx0 * m;
  const float xn1 = xc.y - 0.5f * dx1 * m;
  xt2[i] = make_float2(xn0, xn1);
  fx32[i] = pack_bf16x2(tanhf(xn0), tanhf(xn1));
}

// ---------------- host ----------------

extern "C" void kernel_launch(void* const* d_in, const int* in_sizes, int n_in,
                              void* d_out, int out_size, void* d_ws, size_t ws_size,
                              hipStream_t stream) {
  const float* x = (const float*)d_in[0];
  const int* ei = (const int*)d_in[1];
  const float* w = (const float*)d_in[2];
  const float* mask = (const float*)d_in[3];
  const int E = in_sizes[2];  // 131072
  const int N = in_sizes[3];  // 2000
  const int* src = ei;
  const int* tgt = ei + E;
  float* out = (float*)d_out;

  const int Epad = E + PAD * N;  // room for per-node pad-to-PAD

  size_t off = 0;
  auto alloc = [&](size_t bytes) -> void* {
    off = (off + 255) & ~(size_t)255;
    void* p = (char*)d_ws + off;
    off += bytes;
    return p;
  };
  // cnts + edge arrays contiguous so one zero pass covers all (pad entries -> idx 0, w +0.0)
  int* cntS = (int*)alloc(2048 * 4);
  int* cntT = (int*)alloc(2048 * 4);
  uint32_t* edgeS = (uint32_t*)alloc((size_t)Epad * 4);
  uint32_t* edgeT = (uint32_t*)alloc((size_t)Epad * 4);
  int* offS = (int*)alloc(2048 * 4);
  int* offT = (int*)alloc(2048 * 4);
  int* curS = (int*)alloc(2048 * 4);
  int* curT = (int*)alloc(2048 * 4);
  float2* xt2 = (float2*)alloc((size_t)N * 64 * 8);
  float2* errf2 = (float2*)alloc((size_t)N * 64 * 8);
  uint32_t* fx32 = (uint32_t*)alloc((size_t)N * 64 * 4);
  uint32_t* err32 = (uint32_t*)alloc((size_t)N * 64 * 4);

  const int nzero = (int)(((char*)offS - (char*)cntS) / 4);
  zero_kernel<<<(nzero + 255) / 256, 256, 0, stream>>>((uint32_t*)cntS, nzero);
  hist_kernel<<<(E + 255) / 256, 256, 0, stream>>>(src, tgt, cntS, cntT, E);
  scan_pad_kernel<<<2, 256, 0, stream>>>(cntS, cntT, offS, offT, curS, curT, N);
  scatter_kernel<<<(E + 255) / 256, 256, 0, stream>>>(src, tgt, w, curS, curT, edgeS, edgeT, E);
  tin_kernel<<<(N * 64 + 255) / 256, 256, 0, stream>>>(x, xt2, fx32, N);

  const int pgrid = (N + 3) / 4;  // 4 nodes (waves) per 256-thread block
  for (int it = 0; it < NITER; ++it) {
    phase1_kernel<<<pgrid, 256, 0, stream>>>(xt2, fx32, errf2, err32, offS, edgeS, mask, N);
    phase2_kernel<<<pgrid, 256, 0, stream>>>(xt2, fx32, errf2, err32, offT, edgeT, mask, N);
  }

  tout_kernel<<<(N * NBATCH + 255) / 256, 256, 0, stream>>>(xt2, out, N);
}